// Round 1
// baseline (1991.013 us; speedup 1.0000x reference)
//
#include <hip/hip_runtime.h>
#include <cstddef>

// Problem shape (DotProductAttention_7997229105272): fixed by reference.
constexpr int BATCH = 4;
constexpr int Lq = 4096;
constexpr int Lk = 4096;
constexpr int D  = 512;

constexpr int BM = 128, BN = 128, BK = 16;
constexpr int PAD = 4;   // +4 floats keeps 16B alignment of each LDS row

// C[M,N] = A[M,K] @ op(B);  BT=true: B is [N,K] row-major (NT GEMM, K contig)
//                           BT=false: B is [K,N] row-major (NN GEMM)
// A always row-major K-contiguous. All dims multiples of tile sizes here.
template <bool BT>
__global__ __launch_bounds__(256)
void gemm_f32(const float* __restrict__ A, const float* __restrict__ Bm,
              float* __restrict__ C, int M, int N, int K,
              size_t sA, size_t sB, size_t sC)
{
    __shared__ float As[BK][BM + PAD];
    __shared__ float Bs[BK][BN + PAD];

    const int b  = blockIdx.z;
    A  += (size_t)b * sA;
    Bm += (size_t)b * sB;
    C  += (size_t)b * sC;

    const int m0 = blockIdx.y * BM;
    const int n0 = blockIdx.x * BN;
    const int t  = threadIdx.x;
    const int tx = t & 15;        // 16 thread-cols
    const int ty = t >> 4;        // 16 thread-rows

    float acc[8][8] = {};

    for (int k0 = 0; k0 < K; k0 += BK) {
        // ---- stage A tile (BM x BK), transposed into As[k][m] ----
        // 2048 floats = 512 float4; 256 threads x 2
        #pragma unroll
        for (int i = 0; i < 2; ++i) {
            const int f   = t + i * 256;      // [0,512)
            const int row = f >> 2;           // BK/4 = 4 float4 per row
            const int kq  = (f & 3) * 4;
            const float4 qa = *(const float4*)(A + (size_t)(m0 + row) * K + k0 + kq);
            As[kq + 0][row] = qa.x; As[kq + 1][row] = qa.y;
            As[kq + 2][row] = qa.z; As[kq + 3][row] = qa.w;
        }
        // ---- stage B tile ----
        if (BT) {
            // B rows are N-dim, K contiguous: same transpose as A
            #pragma unroll
            for (int i = 0; i < 2; ++i) {
                const int f   = t + i * 256;
                const int row = f >> 2;
                const int kq  = (f & 3) * 4;
                const float4 vb = *(const float4*)(Bm + (size_t)(n0 + row) * K + k0 + kq);
                Bs[kq + 0][row] = vb.x; Bs[kq + 1][row] = vb.y;
                Bs[kq + 2][row] = vb.z; Bs[kq + 3][row] = vb.w;
            }
        } else {
            // B is [K,N], N contiguous: direct copy rows of BK x BN
            #pragma unroll
            for (int i = 0; i < 2; ++i) {
                const int f  = t + i * 256;   // [0,512)
                const int kr = f >> 5;        // BN/4 = 32 float4 per row
                const int nc = (f & 31) * 4;
                const float4 vb = *(const float4*)(Bm + (size_t)(k0 + kr) * N + n0 + nc);
                *(float4*)&Bs[kr][nc] = vb;
            }
        }
        __syncthreads();

        // ---- 8x8 outer-product accumulate ----
        #pragma unroll
        for (int kk = 0; kk < BK; ++kk) {
            float a[8], bb[8];
            *(float4*)&a[0]  = *(const float4*)&As[kk][ty * 8];
            *(float4*)&a[4]  = *(const float4*)&As[kk][ty * 8 + 4];
            *(float4*)&bb[0] = *(const float4*)&Bs[kk][tx * 8];
            *(float4*)&bb[4] = *(const float4*)&Bs[kk][tx * 8 + 4];
            #pragma unroll
            for (int i = 0; i < 8; ++i)
                #pragma unroll
                for (int j = 0; j < 8; ++j)
                    acc[i][j] = fmaf(a[i], bb[j], acc[i][j]);
        }
        __syncthreads();
    }

    // ---- epilogue: coalesced float4 stores ----
    #pragma unroll
    for (int i = 0; i < 8; ++i) {
        float4* dst = (float4*)(C + (size_t)(m0 + ty * 8 + i) * N + n0 + tx * 8);
        dst[0] = make_float4(acc[i][0], acc[i][1], acc[i][2], acc[i][3]);
        dst[1] = make_float4(acc[i][4], acc[i][5], acc[i][6], acc[i][7]);
    }
}

// In-place row softmax over Lk=4096. One 256-thread block per row; the whole
// row (16 elements/thread) lives in registers: 1 global read + 1 write.
__global__ __launch_bounds__(256)
void softmax_inplace(float* __restrict__ S)
{
    const size_t row = blockIdx.x;
    float* p = S + row * (size_t)Lk;
    const int t = threadIdx.x;

    float4 v[4];
    #pragma unroll
    for (int i = 0; i < 4; ++i) v[i] = ((const float4*)p)[t + i * 256];

    // row max
    float m = -3.0e38f;
    #pragma unroll
    for (int i = 0; i < 4; ++i) {
        m = fmaxf(m, fmaxf(fmaxf(v[i].x, v[i].y), fmaxf(v[i].z, v[i].w)));
    }
    #pragma unroll
    for (int off = 32; off > 0; off >>= 1) m = fmaxf(m, __shfl_xor(m, off));
    __shared__ float redm[4];
    if ((t & 63) == 0) redm[t >> 6] = m;
    __syncthreads();
    m = fmaxf(fmaxf(redm[0], redm[1]), fmaxf(redm[2], redm[3]));

    // exp + row sum
    float s = 0.f;
    #pragma unroll
    for (int i = 0; i < 4; ++i) {
        v[i].x = __expf(v[i].x - m); s += v[i].x;
        v[i].y = __expf(v[i].y - m); s += v[i].y;
        v[i].z = __expf(v[i].z - m); s += v[i].z;
        v[i].w = __expf(v[i].w - m); s += v[i].w;
    }
    #pragma unroll
    for (int off = 32; off > 0; off >>= 1) s += __shfl_xor(s, off);
    __shared__ float reds[4];
    if ((t & 63) == 0) reds[t >> 6] = s;
    __syncthreads();
    s = (reds[0] + reds[1]) + (reds[2] + reds[3]);

    const float inv = 1.0f / s;
    #pragma unroll
    for (int i = 0; i < 4; ++i) {
        v[i].x *= inv; v[i].y *= inv; v[i].z *= inv; v[i].w *= inv;
        ((float4*)p)[t + i * 256] = v[i];
    }
}

extern "C" void kernel_launch(void* const* d_in, const int* in_sizes, int n_in,
                              void* d_out, int out_size, void* d_ws, size_t ws_size,
                              hipStream_t stream)
{
    const float* Q = (const float*)d_in[0];   // [B, Lq, D]
    const float* V = (const float*)d_in[1];   // [B, Lk, D]
    float* ctx  = (float*)d_out;                                  // [B, Lq, D]
    float* attn = (float*)d_out + (size_t)BATCH * Lq * D;         // [B, Lq, Lk]

    const dim3 blk(256);

    // 1) raw scores S = Q @ V^T  -> attn region (in-place softmax next)
    gemm_f32<true><<<dim3(Lk / BN, Lq / BM, BATCH), blk, 0, stream>>>(
        Q, V, attn, Lq, Lk, D,
        (size_t)Lq * D, (size_t)Lk * D, (size_t)Lq * Lk);

    // 2) softmax rows in place
    softmax_inplace<<<dim3(BATCH * Lq), blk, 0, stream>>>(attn);

    // 3) context = attn @ V
    gemm_f32<false><<<dim3(D / BN, Lq / BM, BATCH), blk, 0, stream>>>(
        attn, V, ctx, Lq, D, Lk,
        (size_t)Lq * Lk, (size_t)Lk * D, (size_t)Lq * D);
}

// Round 2
// 909.913 us; speedup vs baseline: 2.1881x; 2.1881x over previous
//
#include <hip/hip_runtime.h>
#include <cstddef>
#include <cstdint>

constexpr int BATCH = 4;
constexpr int Lq = 4096;
constexpr int Lk = 4096;
constexpr int D  = 512;

constexpr int BM = 128, BN = 128, BK = 32;
constexpr int LDA = 40;   // LDS row stride in ushorts: 80B rows -> 16B-aligned b128 frags

using bf16x8 = __attribute__((ext_vector_type(8))) short;
using f32x4  = __attribute__((ext_vector_type(4))) float;

__device__ inline unsigned short f32_to_bf16_rne(float x) {
    uint32_t u = __builtin_bit_cast(uint32_t, x);
    u += 0x7fff + ((u >> 16) & 1);
    return (unsigned short)(u >> 16);
}
__device__ inline float bf16_bits_to_f32(unsigned short h) {
    uint32_t u = ((uint32_t)h) << 16;
    return __builtin_bit_cast(float, u);
}
// split x,y into packed bf16 hi pair + bf16 lo pair (lo = bf16(x - hi))
__device__ inline void split2(float x, float y, uint32_t& hi, uint32_t& lo) {
    unsigned short hx = f32_to_bf16_rne(x);
    unsigned short hy = f32_to_bf16_rne(y);
    unsigned short lx = f32_to_bf16_rne(x - bf16_bits_to_f32(hx));
    unsigned short ly = f32_to_bf16_rne(y - bf16_bits_to_f32(hy));
    hi = (uint32_t)hx | ((uint32_t)hy << 16);
    lo = (uint32_t)lx | ((uint32_t)ly << 16);
}
__device__ inline uint32_t pack2_bf16(float x, float y) {
    return (uint32_t)f32_to_bf16_rne(x) | ((uint32_t)f32_to_bf16_rne(y) << 16);
}

// ---------------- V^T (bf16) into workspace: VT[b][d][lk] -------------------
__global__ __launch_bounds__(256)
void transpose_v_bf16(const float* __restrict__ V, unsigned short* __restrict__ VT)
{
    __shared__ float tile[32][33];
    const int b = blockIdx.z;
    const float* in = V + (size_t)b * Lk * D;
    unsigned short* out = VT + (size_t)b * D * Lk;
    const int lk0 = blockIdx.x * 32;
    const int d0  = blockIdx.y * 32;
    const int c  = threadIdx.x & 31;
    const int r0 = threadIdx.x >> 5;   // 0..7
    #pragma unroll
    for (int i = 0; i < 4; ++i) {
        const int r = r0 + 8 * i;
        tile[r][c] = in[(size_t)(lk0 + r) * D + d0 + c];
    }
    __syncthreads();
    #pragma unroll
    for (int i = 0; i < 4; ++i) {
        const int r = r0 + 8 * i;  // d index within tile
        out[(size_t)(d0 + r) * Lk + lk0 + c] = f32_to_bf16_rne(tile[c][r]);
    }
}

// ------------- GEMM1: S = Q @ V^T, fp32 in, hi/lo bf16 split MFMA -----------
// 128x128 tile, 4 waves of 64x64, mfma_f32_16x16x32_bf16, 3 passes (hh,hl,lh)
__global__ __launch_bounds__(256, 2)
void gemm1_qvt(const float* __restrict__ Qg, const float* __restrict__ Vg,
               float* __restrict__ Sg)
{
    constexpr int K = D;  // 512
    __shared__ alignas(16) unsigned short sAhi[BM * LDA];
    __shared__ alignas(16) unsigned short sAlo[BM * LDA];
    __shared__ alignas(16) unsigned short sBhi[BN * LDA];
    __shared__ alignas(16) unsigned short sBlo[BN * LDA];

    const int b = blockIdx.z;
    const float* A  = Qg + (size_t)b * Lq * D;
    const float* Bp = Vg + (size_t)b * Lk * D;
    float* C = Sg + (size_t)b * Lq * Lk;

    const int m0 = blockIdx.y * BM;
    const int n0 = blockIdx.x * BN;
    const int t    = threadIdx.x;
    const int lane = t & 63;
    const int wave = t >> 6;
    const int wm = (wave >> 1) * 64;
    const int wn = (wave & 1) * 64;
    const int fr = lane & 15;      // frag row index (A: m, B: n)
    const int fq = lane >> 4;      // 0..3, k-quad
    const int sm = t >> 3;         // staging row base (0..31)
    const int sc = t & 7;          // staging float4 col (0..7)

    f32x4 acc[4][4] = {};

    for (int k0 = 0; k0 < K; k0 += BK) {
        if (k0) __syncthreads();   // previous compute done before overwrite
        #pragma unroll
        for (int i = 0; i < 4; ++i) {
            const int m = sm + 32 * i;
            const float4 va = *(const float4*)(A  + (size_t)(m0 + m) * K + k0 + sc * 4);
            const float4 vb = *(const float4*)(Bp + (size_t)(n0 + m) * K + k0 + sc * 4);
            uint2 h, l;
            split2(va.x, va.y, h.x, l.x);
            split2(va.z, va.w, h.y, l.y);
            *(uint2*)&sAhi[m * LDA + sc * 4] = h;
            *(uint2*)&sAlo[m * LDA + sc * 4] = l;
            split2(vb.x, vb.y, h.x, l.x);
            split2(vb.z, vb.w, h.y, l.y);
            *(uint2*)&sBhi[m * LDA + sc * 4] = h;
            *(uint2*)&sBlo[m * LDA + sc * 4] = l;
        }
        __syncthreads();

        bf16x8 ah[4], al[4], bh[4], bl[4];
        #pragma unroll
        for (int x = 0; x < 4; ++x) {
            ah[x] = *(const bf16x8*)&sAhi[(wm + x * 16 + fr) * LDA + fq * 8];
            al[x] = *(const bf16x8*)&sAlo[(wm + x * 16 + fr) * LDA + fq * 8];
            bh[x] = *(const bf16x8*)&sBhi[(wn + x * 16 + fr) * LDA + fq * 8];
            bl[x] = *(const bf16x8*)&sBlo[(wn + x * 16 + fr) * LDA + fq * 8];
        }
        #pragma unroll
        for (int mi = 0; mi < 4; ++mi)
            #pragma unroll
            for (int ni = 0; ni < 4; ++ni) {
                acc[mi][ni] = __builtin_amdgcn_mfma_f32_16x16x32_bf16(ah[mi], bh[ni], acc[mi][ni], 0, 0, 0);
                acc[mi][ni] = __builtin_amdgcn_mfma_f32_16x16x32_bf16(ah[mi], bl[ni], acc[mi][ni], 0, 0, 0);
                acc[mi][ni] = __builtin_amdgcn_mfma_f32_16x16x32_bf16(al[mi], bh[ni], acc[mi][ni], 0, 0, 0);
            }
    }

    // C/D layout (m89-verified): col = lane&15 (n), row = (lane>>4)*4 + reg (m)
    #pragma unroll
    for (int mi = 0; mi < 4; ++mi)
        #pragma unroll
        for (int ni = 0; ni < 4; ++ni)
            #pragma unroll
            for (int r = 0; r < 4; ++r) {
                const int row = m0 + wm + mi * 16 + fq * 4 + r;
                const int col = n0 + wn + ni * 16 + fr;
                C[(size_t)row * Lk + col] = acc[mi][ni][r];
            }
}

// ---------------- softmax rows in place (fp32, 1 read + 1 write) ------------
__global__ __launch_bounds__(256)
void softmax_inplace(float* __restrict__ S)
{
    const size_t row = blockIdx.x;
    float* p = S + row * (size_t)Lk;
    const int t = threadIdx.x;

    float4 v[4];
    #pragma unroll
    for (int i = 0; i < 4; ++i) v[i] = ((const float4*)p)[t + i * 256];

    float m = -3.0e38f;
    #pragma unroll
    for (int i = 0; i < 4; ++i)
        m = fmaxf(m, fmaxf(fmaxf(v[i].x, v[i].y), fmaxf(v[i].z, v[i].w)));
    #pragma unroll
    for (int off = 32; off > 0; off >>= 1) m = fmaxf(m, __shfl_xor(m, off));
    __shared__ float redm[4];
    if ((t & 63) == 0) redm[t >> 6] = m;
    __syncthreads();
    m = fmaxf(fmaxf(redm[0], redm[1]), fmaxf(redm[2], redm[3]));

    float s = 0.f;
    #pragma unroll
    for (int i = 0; i < 4; ++i) {
        v[i].x = __expf(v[i].x - m); s += v[i].x;
        v[i].y = __expf(v[i].y - m); s += v[i].y;
        v[i].z = __expf(v[i].z - m); s += v[i].z;
        v[i].w = __expf(v[i].w - m); s += v[i].w;
    }
    #pragma unroll
    for (int off = 32; off > 0; off >>= 1) s += __shfl_xor(s, off);
    __shared__ float reds[4];
    if ((t & 63) == 0) reds[t >> 6] = s;
    __syncthreads();
    s = (reds[0] + reds[1]) + (reds[2] + reds[3]);

    const float inv = 1.0f / s;
    #pragma unroll
    for (int i = 0; i < 4; ++i) {
        v[i].x *= inv; v[i].y *= inv; v[i].z *= inv; v[i].w *= inv;
        ((float4*)p)[t + i * 256] = v[i];
    }
}

// ------------- GEMM2: ctx = P @ V  (P fp32 -> bf16, VT bf16, NT) ------------
__global__ __launch_bounds__(256, 2)
void gemm2_pv(const float* __restrict__ Pg, const unsigned short* __restrict__ VTg,
              float* __restrict__ Cg)
{
    constexpr int K = Lk;   // 4096
    constexpr int N = D;    // 512
    __shared__ alignas(16) unsigned short sA[BM * LDA];
    __shared__ alignas(16) unsigned short sB[BN * LDA];

    const int b = blockIdx.z;
    const float*          A  = Pg  + (size_t)b * Lq * Lk;
    const unsigned short* Bp = VTg + (size_t)b * D * Lk;
    float* C = Cg + (size_t)b * Lq * D;

    const int m0 = blockIdx.y * BM;
    const int n0 = blockIdx.x * BN;
    const int t    = threadIdx.x;
    const int lane = t & 63;
    const int wave = t >> 6;
    const int wm = (wave >> 1) * 64;
    const int wn = (wave & 1) * 64;
    const int fr = lane & 15;
    const int fq = lane >> 4;
    const int sm = t >> 3;     // A staging row base
    const int sc = t & 7;
    const int bn = t >> 2;     // B staging row base (0..63)
    const int bc = t & 3;      // B staging 16B col

    f32x4 acc[4][4] = {};

    for (int k0 = 0; k0 < K; k0 += BK) {
        if (k0) __syncthreads();
        #pragma unroll
        for (int i = 0; i < 4; ++i) {
            const int m = sm + 32 * i;
            const float4 va = *(const float4*)(A + (size_t)(m0 + m) * K + k0 + sc * 4);
            uint2 h;
            h.x = pack2_bf16(va.x, va.y);
            h.y = pack2_bf16(va.z, va.w);
            *(uint2*)&sA[m * LDA + sc * 4] = h;
        }
        #pragma unroll
        for (int i = 0; i < 2; ++i) {
            const int n = bn + 64 * i;
            const bf16x8 vb = *(const bf16x8*)(Bp + (size_t)(n0 + n) * K + k0 + bc * 8);
            *(bf16x8*)&sB[n * LDA + bc * 8] = vb;
        }
        __syncthreads();

        bf16x8 af[4], bf[4];
        #pragma unroll
        for (int x = 0; x < 4; ++x) {
            af[x] = *(const bf16x8*)&sA[(wm + x * 16 + fr) * LDA + fq * 8];
            bf[x] = *(const bf16x8*)&sB[(wn + x * 16 + fr) * LDA + fq * 8];
        }
        #pragma unroll
        for (int mi = 0; mi < 4; ++mi)
            #pragma unroll
            for (int ni = 0; ni < 4; ++ni)
                acc[mi][ni] = __builtin_amdgcn_mfma_f32_16x16x32_bf16(af[mi], bf[ni], acc[mi][ni], 0, 0, 0);
    }

    #pragma unroll
    for (int mi = 0; mi < 4; ++mi)
        #pragma unroll
        for (int ni = 0; ni < 4; ++ni)
            #pragma unroll
            for (int r = 0; r < 4; ++r) {
                const int row = m0 + wm + mi * 16 + fq * 4 + r;
                const int col = n0 + wn + ni * 16 + fr;
                C[(size_t)row * N + col] = acc[mi][ni][r];
            }
}

extern "C" void kernel_launch(void* const* d_in, const int* in_sizes, int n_in,
                              void* d_out, int out_size, void* d_ws, size_t ws_size,
                              hipStream_t stream)
{
    const float* Q = (const float*)d_in[0];   // [B, Lq, D]
    const float* V = (const float*)d_in[1];   // [B, Lk, D]
    float* ctx  = (float*)d_out;                              // [B, Lq, D]
    float* attn = (float*)d_out + (size_t)BATCH * Lq * D;     // [B, Lq, Lk]
    // workspace: V^T in bf16, [B][D][Lk] = 16 MiB (requires ws_size >= 16 MiB)
    unsigned short* VT = (unsigned short*)d_ws;

    transpose_v_bf16<<<dim3(Lk / 32, D / 32, BATCH), 256, 0, stream>>>(V, VT);
    gemm1_qvt<<<dim3(Lk / BN, Lq / BM, BATCH), 256, 0, stream>>>(Q, V, attn);
    softmax_inplace<<<dim3(BATCH * Lq), 256, 0, stream>>>(attn);
    gemm2_pv<<<dim3(D / BN, Lq / BM, BATCH), 256, 0, stream>>>(attn, VT, ctx);
}

// Round 3
// 751.393 us; speedup vs baseline: 2.6498x; 1.2110x over previous
//
#include <hip/hip_runtime.h>
#include <cstddef>
#include <cstdint>

typedef unsigned short u16;

constexpr int BATCH = 4;
constexpr int Lq = 4096;
constexpr int Lk = 4096;
constexpr int D  = 512;

constexpr int BM = 128, BN = 128, BK = 32;
constexpr int LDA = 40;   // fallback-path LDS stride

using bf16x8 = __attribute__((ext_vector_type(8))) short;
using f32x4  = __attribute__((ext_vector_type(4))) float;

__device__ inline u16 f32_to_bf16_rne(float x) {
    uint32_t u = __builtin_bit_cast(uint32_t, x);
    u += 0x7fff + ((u >> 16) & 1);
    return (u16)(u >> 16);
}
__device__ inline float bf16_bits_to_f32(u16 h) {
    uint32_t u = ((uint32_t)h) << 16;
    return __builtin_bit_cast(float, u);
}
__device__ inline void split2(float x, float y, uint32_t& hi, uint32_t& lo) {
    u16 hx = f32_to_bf16_rne(x);
    u16 hy = f32_to_bf16_rne(y);
    u16 lx = f32_to_bf16_rne(x - bf16_bits_to_f32(hx));
    u16 ly = f32_to_bf16_rne(y - bf16_bits_to_f32(hy));
    hi = (uint32_t)hx | ((uint32_t)hy << 16);
    lo = (uint32_t)lx | ((uint32_t)ly << 16);
}
__device__ inline uint32_t pack2_bf16(float x, float y) {
    return (uint32_t)f32_to_bf16_rne(x) | ((uint32_t)f32_to_bf16_rne(y) << 16);
}
// async global->LDS, 16B/lane; LDS dest is wave-uniform base + lane*16
__device__ inline void gld16(const u16* g, u16* l) {
    __builtin_amdgcn_global_load_lds(
        (const __attribute__((address_space(1))) void*)g,
        (__attribute__((address_space(3))) void*)l, 16, 0, 0);
}

// ---------------- pre-split: fp32 -> bf16 hi + bf16 lo ---------------------
__global__ __launch_bounds__(256)
void split_bf16(const float* __restrict__ src, u16* __restrict__ hi,
                u16* __restrict__ lo, int n4)
{
    const int i = blockIdx.x * 256 + threadIdx.x;
    if (i >= n4) return;
    const float4 v = ((const float4*)src)[i];
    uint2 h, l;
    split2(v.x, v.y, h.x, l.x);
    split2(v.z, v.w, h.y, l.y);
    ((uint2*)hi)[i] = h;
    ((uint2*)lo)[i] = l;
}

// ---------------- V^T (bf16) into workspace: VT[b][d][lk] -------------------
__global__ __launch_bounds__(256)
void transpose_v_bf16(const float* __restrict__ V, u16* __restrict__ VT)
{
    __shared__ float tile[32][33];
    const int b = blockIdx.z;
    const float* in = V + (size_t)b * Lk * D;
    u16* out = VT + (size_t)b * D * Lk;
    const int lk0 = blockIdx.x * 32;
    const int d0  = blockIdx.y * 32;
    const int c  = threadIdx.x & 31;
    const int r0 = threadIdx.x >> 5;
    #pragma unroll
    for (int i = 0; i < 4; ++i) {
        const int r = r0 + 8 * i;
        tile[r][c] = in[(size_t)(lk0 + r) * D + d0 + c];
    }
    __syncthreads();
    #pragma unroll
    for (int i = 0; i < 4; ++i) {
        const int r = r0 + 8 * i;
        out[(size_t)(d0 + r) * Lk + lk0 + c] = f32_to_bf16_rne(tile[c][r]);
    }
}

// ---- GEMM1: S = Q@V^T from pre-split bf16 hi/lo, global_load_lds staging ---
__global__ __launch_bounds__(256, 3)
void gemm1_mfma(const u16* __restrict__ Qhi, const u16* __restrict__ Qlo,
                const u16* __restrict__ Vhi, const u16* __restrict__ Vlo,
                float* __restrict__ Sg)
{
    constexpr int K = D;  // 512
    __shared__ u16 sAhi[BM * BK];   // 8 KB each, unpadded (lds-dma layout)
    __shared__ u16 sAlo[BM * BK];
    __shared__ u16 sBhi[BN * BK];
    __shared__ u16 sBlo[BN * BK];

    const int b = blockIdx.z;
    const u16* Ah = Qhi + (size_t)b * Lq * D;
    const u16* Al = Qlo + (size_t)b * Lq * D;
    const u16* Bh = Vhi + (size_t)b * Lk * D;
    const u16* Bl = Vlo + (size_t)b * Lk * D;
    float* C = Sg + (size_t)b * Lq * Lk;

    const int m0 = blockIdx.y * BM;
    const int n0 = blockIdx.x * BN;
    const int t = threadIdx.x, lane = t & 63, wave = t >> 6;
    const int wm = (wave >> 1) * 64, wn = (wave & 1) * 64;
    const int fr = lane & 15, fq = lane >> 4;

    // staging: tile = 512 16B-chunks, row-major [row][k-chunk]; window v (1KB)
    // = rows [16v,16v+16). wave stages windows {w, w+4} of each tile.
    const int r0  = wave * 16 + (lane >> 2);
    const int r1  = r0 + 64;
    const int kc8 = (lane & 3) * 8;
    const int oA0 = (m0 + r0) * K + kc8;
    const int oA1 = (m0 + r1) * K + kc8;
    const int oB0 = (n0 + r0) * K + kc8;
    const int oB1 = (n0 + r1) * K + kc8;
    u16* dst0 = nullptr; // computed per tile below
    const int w0 = wave * 512, w1 = (wave + 4) * 512;   // u16 offsets

    f32x4 acc[4][4] = {};

    for (int k0 = 0; k0 < K; k0 += BK) {
        if (k0) __syncthreads();
        gld16(Ah + oA0 + k0, &sAhi[w0]);
        gld16(Ah + oA1 + k0, &sAhi[w1]);
        gld16(Al + oA0 + k0, &sAlo[w0]);
        gld16(Al + oA1 + k0, &sAlo[w1]);
        gld16(Bh + oB0 + k0, &sBhi[w0]);
        gld16(Bh + oB1 + k0, &sBhi[w1]);
        gld16(Bl + oB0 + k0, &sBlo[w0]);
        gld16(Bl + oB1 + k0, &sBlo[w1]);
        __syncthreads();   // implies vmcnt(0): lds-dma complete

        bf16x8 ah[4], al[4], bh[4], bl[4];
        #pragma unroll
        for (int x = 0; x < 4; ++x) {
            const int ra = (wm + x * 16 + fr) * BK + fq * 8;
            const int rb = (wn + x * 16 + fr) * BK + fq * 8;
            ah[x] = *(const bf16x8*)&sAhi[ra];
            al[x] = *(const bf16x8*)&sAlo[ra];
            bh[x] = *(const bf16x8*)&sBhi[rb];
            bl[x] = *(const bf16x8*)&sBlo[rb];
        }
        #pragma unroll
        for (int mi = 0; mi < 4; ++mi)
            #pragma unroll
            for (int ni = 0; ni < 4; ++ni) {
                acc[mi][ni] = __builtin_amdgcn_mfma_f32_16x16x32_bf16(ah[mi], bh[ni], acc[mi][ni], 0, 0, 0);
                acc[mi][ni] = __builtin_amdgcn_mfma_f32_16x16x32_bf16(ah[mi], bl[ni], acc[mi][ni], 0, 0, 0);
                acc[mi][ni] = __builtin_amdgcn_mfma_f32_16x16x32_bf16(al[mi], bh[ni], acc[mi][ni], 0, 0, 0);
            }
    }
    (void)dst0;

    #pragma unroll
    for (int mi = 0; mi < 4; ++mi)
        #pragma unroll
        for (int ni = 0; ni < 4; ++ni)
            #pragma unroll
            for (int r = 0; r < 4; ++r) {
                const int row = m0 + wm + mi * 16 + fq * 4 + r;
                const int col = n0 + wn + ni * 16 + fr;
                C[(size_t)row * Lk + col] = acc[mi][ni][r];
            }
}

// -------- softmax rows in place; optionally emit bf16 copy of P ------------
__global__ __launch_bounds__(256)
void softmax_inplace(float* __restrict__ S, u16* __restrict__ Pb)
{
    const size_t row = blockIdx.x;
    float* p = S + row * (size_t)Lk;
    const int t = threadIdx.x;

    float4 v[4];
    #pragma unroll
    for (int i = 0; i < 4; ++i) v[i] = ((const float4*)p)[t + i * 256];

    float m = -3.0e38f;
    #pragma unroll
    for (int i = 0; i < 4; ++i)
        m = fmaxf(m, fmaxf(fmaxf(v[i].x, v[i].y), fmaxf(v[i].z, v[i].w)));
    #pragma unroll
    for (int off = 32; off > 0; off >>= 1) m = fmaxf(m, __shfl_xor(m, off));
    __shared__ float redm[4];
    if ((t & 63) == 0) redm[t >> 6] = m;
    __syncthreads();
    m = fmaxf(fmaxf(redm[0], redm[1]), fmaxf(redm[2], redm[3]));

    float s = 0.f;
    #pragma unroll
    for (int i = 0; i < 4; ++i) {
        v[i].x = __expf(v[i].x - m); s += v[i].x;
        v[i].y = __expf(v[i].y - m); s += v[i].y;
        v[i].z = __expf(v[i].z - m); s += v[i].z;
        v[i].w = __expf(v[i].w - m); s += v[i].w;
    }
    #pragma unroll
    for (int off = 32; off > 0; off >>= 1) s += __shfl_xor(s, off);
    __shared__ float reds[4];
    if ((t & 63) == 0) reds[t >> 6] = s;
    __syncthreads();
    s = (reds[0] + reds[1]) + (reds[2] + reds[3]);

    const float inv = 1.0f / s;
    u16* prow = Pb ? Pb + row * (size_t)Lk : nullptr;
    #pragma unroll
    for (int i = 0; i < 4; ++i) {
        v[i].x *= inv; v[i].y *= inv; v[i].z *= inv; v[i].w *= inv;
        ((float4*)p)[t + i * 256] = v[i];
        if (prow) {
            ushort4 h = make_ushort4(f32_to_bf16_rne(v[i].x), f32_to_bf16_rne(v[i].y),
                                     f32_to_bf16_rne(v[i].z), f32_to_bf16_rne(v[i].w));
            ((ushort4*)prow)[t + i * 256] = h;
        }
    }
}

// ------ GEMM2: ctx = P @ V, pure bf16 NT (Pb [Lq][Lk], VT [D][Lk]) ---------
__global__ __launch_bounds__(256, 3)
void gemm2_mfma(const u16* __restrict__ Pg, const u16* __restrict__ VTg,
                float* __restrict__ Cg)
{
    constexpr int K = Lk;   // 4096
    constexpr int N = D;    // 512
    __shared__ u16 sA[BM * BK];
    __shared__ u16 sB[BN * BK];

    const int b = blockIdx.z;
    const u16* A  = Pg  + (size_t)b * Lq * Lk;
    const u16* Bp = VTg + (size_t)b * (size_t)D * Lk;
    float* C = Cg + (size_t)b * Lq * D;

    const int m0 = blockIdx.y * BM;
    const int n0 = blockIdx.x * BN;
    const int t = threadIdx.x, lane = t & 63, wave = t >> 6;
    const int wm = (wave >> 1) * 64, wn = (wave & 1) * 64;
    const int fr = lane & 15, fq = lane >> 4;

    const int r0  = wave * 16 + (lane >> 2);
    const int r1  = r0 + 64;
    const int kc8 = (lane & 3) * 8;
    const int oA0 = (m0 + r0) * K + kc8;
    const int oA1 = (m0 + r1) * K + kc8;
    const int oB0 = (n0 + r0) * K + kc8;
    const int oB1 = (n0 + r1) * K + kc8;
    const int w0 = wave * 512, w1 = (wave + 4) * 512;

    f32x4 acc[4][4] = {};

    for (int k0 = 0; k0 < K; k0 += BK) {
        if (k0) __syncthreads();
        gld16(A  + oA0 + k0, &sA[w0]);
        gld16(A  + oA1 + k0, &sA[w1]);
        gld16(Bp + oB0 + k0, &sB[w0]);
        gld16(Bp + oB1 + k0, &sB[w1]);
        __syncthreads();

        bf16x8 af[4], bf[4];
        #pragma unroll
        for (int x = 0; x < 4; ++x) {
            af[x] = *(const bf16x8*)&sA[(wm + x * 16 + fr) * BK + fq * 8];
            bf[x] = *(const bf16x8*)&sB[(wn + x * 16 + fr) * BK + fq * 8];
        }
        #pragma unroll
        for (int mi = 0; mi < 4; ++mi)
            #pragma unroll
            for (int ni = 0; ni < 4; ++ni)
                acc[mi][ni] = __builtin_amdgcn_mfma_f32_16x16x32_bf16(af[mi], bf[ni], acc[mi][ni], 0, 0, 0);
    }

    #pragma unroll
    for (int mi = 0; mi < 4; ++mi)
        #pragma unroll
        for (int ni = 0; ni < 4; ++ni)
            #pragma unroll
            for (int r = 0; r < 4; ++r) {
                const int row = m0 + wm + mi * 16 + fq * 4 + r;
                const int col = n0 + wn + ni * 16 + fr;
                C[(size_t)row * N + col] = acc[mi][ni][r];
            }
}

// ======================= round-2 fallback kernels ==========================
__global__ __launch_bounds__(256, 2)
void gemm1_r2(const float* __restrict__ Qg, const float* __restrict__ Vg,
              float* __restrict__ Sg)
{
    constexpr int K = D;
    __shared__ alignas(16) u16 sAhi[BM * LDA];
    __shared__ alignas(16) u16 sAlo[BM * LDA];
    __shared__ alignas(16) u16 sBhi[BN * LDA];
    __shared__ alignas(16) u16 sBlo[BN * LDA];

    const int b = blockIdx.z;
    const float* A  = Qg + (size_t)b * Lq * D;
    const float* Bp = Vg + (size_t)b * Lk * D;
    float* C = Sg + (size_t)b * Lq * Lk;

    const int m0 = blockIdx.y * BM;
    const int n0 = blockIdx.x * BN;
    const int t = threadIdx.x, lane = t & 63, wave = t >> 6;
    const int wm = (wave >> 1) * 64, wn = (wave & 1) * 64;
    const int fr = lane & 15, fq = lane >> 4;
    const int sm = t >> 3, sc = t & 7;

    f32x4 acc[4][4] = {};

    for (int k0 = 0; k0 < K; k0 += BK) {
        if (k0) __syncthreads();
        #pragma unroll
        for (int i = 0; i < 4; ++i) {
            const int m = sm + 32 * i;
            const float4 va = *(const float4*)(A  + (size_t)(m0 + m) * K + k0 + sc * 4);
            const float4 vb = *(const float4*)(Bp + (size_t)(n0 + m) * K + k0 + sc * 4);
            uint2 h, l;
            split2(va.x, va.y, h.x, l.x);
            split2(va.z, va.w, h.y, l.y);
            *(uint2*)&sAhi[m * LDA + sc * 4] = h;
            *(uint2*)&sAlo[m * LDA + sc * 4] = l;
            split2(vb.x, vb.y, h.x, l.x);
            split2(vb.z, vb.w, h.y, l.y);
            *(uint2*)&sBhi[m * LDA + sc * 4] = h;
            *(uint2*)&sBlo[m * LDA + sc * 4] = l;
        }
        __syncthreads();

        bf16x8 ah[4], al[4], bh[4], bl[4];
        #pragma unroll
        for (int x = 0; x < 4; ++x) {
            ah[x] = *(const bf16x8*)&sAhi[(wm + x * 16 + fr) * LDA + fq * 8];
            al[x] = *(const bf16x8*)&sAlo[(wm + x * 16 + fr) * LDA + fq * 8];
            bh[x] = *(const bf16x8*)&sBhi[(wn + x * 16 + fr) * LDA + fq * 8];
            bl[x] = *(const bf16x8*)&sBlo[(wn + x * 16 + fr) * LDA + fq * 8];
        }
        #pragma unroll
        for (int mi = 0; mi < 4; ++mi)
            #pragma unroll
            for (int ni = 0; ni < 4; ++ni) {
                acc[mi][ni] = __builtin_amdgcn_mfma_f32_16x16x32_bf16(ah[mi], bh[ni], acc[mi][ni], 0, 0, 0);
                acc[mi][ni] = __builtin_amdgcn_mfma_f32_16x16x32_bf16(ah[mi], bl[ni], acc[mi][ni], 0, 0, 0);
                acc[mi][ni] = __builtin_amdgcn_mfma_f32_16x16x32_bf16(al[mi], bh[ni], acc[mi][ni], 0, 0, 0);
            }
    }

    #pragma unroll
    for (int mi = 0; mi < 4; ++mi)
        #pragma unroll
        for (int ni = 0; ni < 4; ++ni)
            #pragma unroll
            for (int r = 0; r < 4; ++r) {
                const int row = m0 + wm + mi * 16 + fq * 4 + r;
                const int col = n0 + wn + ni * 16 + fr;
                C[(size_t)row * Lk + col] = acc[mi][ni][r];
            }
}

__global__ __launch_bounds__(256, 2)
void gemm2_r2(const float* __restrict__ Pg, const u16* __restrict__ VTg,
              float* __restrict__ Cg)
{
    constexpr int K = Lk;
    constexpr int N = D;
    __shared__ alignas(16) u16 sA[BM * LDA];
    __shared__ alignas(16) u16 sB[BN * LDA];

    const int b = blockIdx.z;
    const float* A  = Pg  + (size_t)b * Lq * Lk;
    const u16*   Bp = VTg + (size_t)b * (size_t)D * Lk;
    float* C = Cg + (size_t)b * Lq * D;

    const int m0 = blockIdx.y * BM;
    const int n0 = blockIdx.x * BN;
    const int t = threadIdx.x, lane = t & 63, wave = t >> 6;
    const int wm = (wave >> 1) * 64, wn = (wave & 1) * 64;
    const int fr = lane & 15, fq = lane >> 4;
    const int sm = t >> 3, sc = t & 7;
    const int bn = t >> 2, bc = t & 3;

    f32x4 acc[4][4] = {};

    for (int k0 = 0; k0 < K; k0 += BK) {
        if (k0) __syncthreads();
        #pragma unroll
        for (int i = 0; i < 4; ++i) {
            const int m = sm + 32 * i;
            const float4 va = *(const float4*)(A + (size_t)(m0 + m) * K + k0 + sc * 4);
            uint2 h;
            h.x = pack2_bf16(va.x, va.y);
            h.y = pack2_bf16(va.z, va.w);
            *(uint2*)&sA[m * LDA + sc * 4] = h;
        }
        #pragma unroll
        for (int i = 0; i < 2; ++i) {
            const int n = bn + 64 * i;
            const bf16x8 vb = *(const bf16x8*)(Bp + (size_t)(n0 + n) * K + k0 + bc * 8);
            *(bf16x8*)&sB[n * LDA + bc * 8] = vb;
        }
        __syncthreads();

        bf16x8 af[4], bf[4];
        #pragma unroll
        for (int x = 0; x < 4; ++x) {
            af[x] = *(const bf16x8*)&sA[(wm + x * 16 + fr) * LDA + fq * 8];
            bf[x] = *(const bf16x8*)&sB[(wn + x * 16 + fr) * LDA + fq * 8];
        }
        #pragma unroll
        for (int mi = 0; mi < 4; ++mi)
            #pragma unroll
            for (int ni = 0; ni < 4; ++ni)
                acc[mi][ni] = __builtin_amdgcn_mfma_f32_16x16x32_bf16(af[mi], bf[ni], acc[mi][ni], 0, 0, 0);
    }

    #pragma unroll
    for (int mi = 0; mi < 4; ++mi)
        #pragma unroll
        for (int ni = 0; ni < 4; ++ni)
            #pragma unroll
            for (int r = 0; r < 4; ++r) {
                const int row = m0 + wm + mi * 16 + fq * 4 + r;
                const int col = n0 + wn + ni * 16 + fr;
                C[(size_t)row * N + col] = acc[mi][ni][r];
            }
}

extern "C" void kernel_launch(void* const* d_in, const int* in_sizes, int n_in,
                              void* d_out, int out_size, void* d_ws, size_t ws_size,
                              hipStream_t stream)
{
    const float* Q = (const float*)d_in[0];   // [B, Lq, D]
    const float* V = (const float*)d_in[1];   // [B, Lk, D]
    float* ctx  = (float*)d_out;                              // [B, Lq, D]
    float* attn = (float*)d_out + (size_t)BATCH * Lq * D;     // [B, Lq, Lk]

    constexpr size_t NQ = (size_t)BATCH * Lq * D;    // 8,388,608 elems
    constexpr size_t NP = (size_t)BATCH * Lq * Lk;   // 67,108,864 elems
    const size_t need = (5 * NQ + NP) * sizeof(u16); // ~208 MiB

    if (ws_size >= need) {
        u16* Qhi = (u16*)d_ws;
        u16* Qlo = Qhi + NQ;
        u16* Vhi = Qlo + NQ;
        u16* Vlo = Vhi + NQ;
        u16* VT  = Vlo + NQ;
        u16* Pb  = VT  + NQ;

        const int n4 = (int)(NQ / 4);
        split_bf16<<<dim3(n4 / 256), 256, 0, stream>>>(Q, Qhi, Qlo, n4);
        split_bf16<<<dim3(n4 / 256), 256, 0, stream>>>(V, Vhi, Vlo, n4);
        transpose_v_bf16<<<dim3(Lk / 32, D / 32, BATCH), 256, 0, stream>>>(V, VT);
        gemm1_mfma<<<dim3(Lk / BN, Lq / BM, BATCH), 256, 0, stream>>>(Qhi, Qlo, Vhi, Vlo, attn);
        softmax_inplace<<<dim3(BATCH * Lq), 256, 0, stream>>>(attn, Pb);
        gemm2_mfma<<<dim3(D / BN, Lq / BM, BATCH), 256, 0, stream>>>(Pb, VT, ctx);
    } else {
        // round-2 fallback: only needs 16.8 MiB for VT
        u16* VT = (u16*)d_ws;
        transpose_v_bf16<<<dim3(Lk / 32, D / 32, BATCH), 256, 0, stream>>>(V, VT);
        gemm1_r2<<<dim3(Lk / BN, Lq / BM, BATCH), 256, 0, stream>>>(Q, V, attn);
        softmax_inplace<<<dim3(BATCH * Lq), 256, 0, stream>>>(attn, nullptr);
        gemm2_r2<<<dim3(D / BN, Lq / BM, BATCH), 256, 0, stream>>>(attn, VT, ctx);
    }
}